// Round 1
// 2964.826 us; speedup vs baseline: 3.6635x; 3.6635x over previous
//
#include <hip/hip_runtime.h>
#include <hip/hip_bf16.h>
#include <math.h>

typedef short s8v __attribute__((ext_vector_type(8)));
typedef float f4v __attribute__((ext_vector_type(4)));
typedef float f8v __attribute__((ext_vector_type(8)));

#define D_    768
#define M_    5
#define DS_   768
#define NH_   12
#define B_    8
#define V_    512
#define S_    128
#define T_    16
#define A_    8
#define DIN_  6144
#define NP    (1 << 30)

// split fp32 x into bf16 hi (truncate) + bf16 lo (truncate of exact residual)
__device__ __forceinline__ void split8(const f8v& x, s8v& hi, s8v& lo) {
#pragma unroll
    for (int j = 0; j < 8; j++) {
        unsigned xu = __float_as_uint(x[j]);
        float hf = __uint_as_float(xu & 0xFFFF0000u);
        float r  = x[j] - hf;                       // exact in fp32
        hi[j] = (short)(xu >> 16);
        lo[j] = (short)(__float_as_uint(r) >> 16);
    }
}

// ===== generalized split-bf16 MFMA GEMM: C = act(scale*(A @ W^T) + bias [+res]) =====
// A row r (within z-slice): A + ab + aoff + (r/arpb)*abst + (r%arpb)*lda, frag k-offset added.
// 3-level z-batch: zh_all=z/zdiv, zl=z%zdiv, zt=zh_all/zdiv2, zh=zh_all%zdiv2:
//   ab = zt*az1b + zh*az1 + zl*az2 (same pattern for W with wz*, out with oz*).
// W row n: W + woff + wb + n*ldw.
// Out: ob + (row/orpb)*ostride + (row%orpb)*osub + coff + col*cscale.
// 256 thr = 4 waves; tile 64(M) x 128(N); wave w covers cols [w*32, w*32+32).
template<int ACT, bool RES>
__global__ __launch_bounds__(256)
void mm(const float* __restrict__ A, int lda, int arpb, long abst, long aoff,
        long az1b, long az1, long az2, int zdiv2, int zdiv,
        const float* __restrict__ W, long woff, int ldw, long wz1b, long wz1, long wz2,
        const float* __restrict__ bias, long boff, float scale,
        float* __restrict__ Cout, long oz1b, long oz1, long oz2,
        int orpb, long ostride, long osub, long coff, long cscale,
        const float* __restrict__ res,
        int M, int N, int K)
{
    const int tid = threadIdx.x;
    const int w = tid >> 6, l = tid & 63, q = l >> 4, ln = l & 15;
    const int n0 = blockIdx.x * 128 + w * 32;
    const int m0 = blockIdx.y * 64;
    const int z = blockIdx.z;
    int zh_all = z / zdiv, zl = z - zh_all * zdiv;
    int zt = zh_all / zdiv2, zh = zh_all - zt * zdiv2;
    long ab = (long)zt * az1b + (long)zh * az1 + (long)zl * az2;
    long wb = (long)zt * wz1b + (long)zh * wz1 + (long)zl * wz2;
    long ob = (long)zt * oz1b + (long)zh * oz1 + (long)zl * oz2;

    const float* arow[4];
#pragma unroll
    for (int mf = 0; mf < 4; mf++) {
        int rm = m0 + mf * 16 + ln;
        if (rm > M - 1) rm = M - 1;
        long ro = ab + aoff + (long)(rm / arpb) * abst + (long)(rm % arpb) * lda;
        arow[mf] = A + ro + q * 8;
    }
    const float* wrow[2];
#pragma unroll
    for (int nf = 0; nf < 2; nf++)
        wrow[nf] = W + woff + wb + (long)(n0 + nf * 16 + ln) * ldw + q * 8;

    f4v acc[4][2];
#pragma unroll
    for (int mf = 0; mf < 4; mf++)
#pragma unroll
        for (int nf = 0; nf < 2; nf++)
#pragma unroll
            for (int r = 0; r < 4; r++) acc[mf][nf][r] = 0.f;

    for (int k = 0; k < K; k += 32) {
        s8v ah[4], al[4], bh[2], bl[2];
#pragma unroll
        for (int mf = 0; mf < 4; mf++) {
            f8v av = *(const f8v*)(const void*)(arow[mf] + k);
            split8(av, ah[mf], al[mf]);
        }
#pragma unroll
        for (int nf = 0; nf < 2; nf++) {
            f8v wv = *(const f8v*)(const void*)(wrow[nf] + k);
            split8(wv, bh[nf], bl[nf]);
        }
#pragma unroll
        for (int mf = 0; mf < 4; mf++)
#pragma unroll
            for (int nf = 0; nf < 2; nf++) {
                acc[mf][nf] = __builtin_amdgcn_mfma_f32_16x16x32_bf16(ah[mf], bh[nf], acc[mf][nf], 0, 0, 0);
                acc[mf][nf] = __builtin_amdgcn_mfma_f32_16x16x32_bf16(ah[mf], bl[nf], acc[mf][nf], 0, 0, 0);
                acc[mf][nf] = __builtin_amdgcn_mfma_f32_16x16x32_bf16(al[mf], bh[nf], acc[mf][nf], 0, 0, 0);
            }
    }

#pragma unroll
    for (int mf = 0; mf < 4; mf++) {
#pragma unroll
        for (int r = 0; r < 4; r++) {
            int row = m0 + mf * 16 + q * 4 + r;
            if (row >= M) continue;
#pragma unroll
            for (int nf = 0; nf < 2; nf++) {
                int col = n0 + nf * 16 + ln;
                if (col >= N) continue;
                float v = acc[mf][nf][r];
                v *= scale;
                if (bias) v += bias[boff + col];
                if (ACT) v = fmaxf(v, 0.f);
                if (RES) v += res[(size_t)(row >> 3) * 768 + col];
                long o = ob + (long)(row / orpb) * ostride + (long)(row % orpb) * osub
                       + coff + (long)col * cscale;
                Cout[o] = v;
            }
        }
    }
}

// row-wise in-place softmax; grid.x = #rows, 256 threads
__global__ void softmax_rows(float* __restrict__ sc, int len)
{
    float* p = sc + (size_t)blockIdx.x * len;
    __shared__ float red[256];
    int tid = threadIdx.x;
    float m = -1e30f;
    for (int i = tid; i < len; i += 256) m = fmaxf(m, p[i]);
    red[tid] = m; __syncthreads();
    for (int o = 128; o > 0; o >>= 1) {
        if (tid < o) red[tid] = fmaxf(red[tid], red[tid + o]);
        __syncthreads();
    }
    float mx = red[0]; __syncthreads();
    float s = 0.f;
    for (int i = tid; i < len; i += 256) { float e = expf(p[i] - mx); p[i] = e; s += e; }
    red[tid] = s; __syncthreads();
    for (int o = 128; o > 0; o >>= 1) {
        if (tid < o) red[tid] += red[tid + o];
        __syncthreads();
    }
    float inv = 1.f / red[0]; __syncthreads();
    for (int i = tid; i < len; i += 256) p[i] *= inv;
}

// wmask over chunk: block z = tch*8 + b; sc2 laid [tch][b][h][8][128]
__global__ void wmask_kernel(const float* __restrict__ sc2, float* __restrict__ wmask)
{
    int z = blockIdx.x;
    const float* src = sc2 + (size_t)z * 12288;
    float* dst = wmask + (size_t)z * 1024;
    for (int idx = threadIdx.x; idx < 1024; idx += 256) {
        float s = 0.f;
        for (int h = 0; h < NH_; h++) s += src[h * 1024 + idx];
        dst[idx] = s * (1.f / 12.f);
    }
}

// GRU states for all 8 candidate predecessors of every (t, b, a).
// chunk rows: R = tloc*512 + b*64 + ap*8 + a  (ap = candidate argmax for b at t-1)
// t = t0c + tloc.  t==0: predecessor is state0 (gh0), identical for all ap.
__global__ void gru_cand(const float* __restrict__ gi_all, const float* __restrict__ ghall,
                         const float* __restrict__ gh0, const float* __restrict__ pre_all,
                         const float* __restrict__ s0p, float* __restrict__ stc, int t0c)
{
    long idx = (long)blockIdx.x * 256 + threadIdx.x;   // exactly nt*512*768
    int c = (int)(idx % 768);
    long r = idx / 768;
    int tloc = (int)(r / 512), rem = (int)(r % 512);
    int b = rem >> 6, ap = (rem >> 3) & 7, a = rem & 7;
    int t = t0c + tloc;
    const float* gi = gi_all + ((long)t * 64 + b * 8 + a) * 2304;
    const float* gh; float hv;
    if (t == 0) { gh = gh0; hv = s0p[c]; }
    else {
        long j = (long)(t - 1) * 64 + b * 8 + ap;
        gh = ghall + j * 2304;
        hv = pre_all[j * 768 + c];
    }
    float ir  = gi[c], iz = gi[768 + c], inn = gi[1536 + c];
    float rg = 1.f / (1.f + expf(-(ir + gh[c])));
    float zg = 1.f / (1.f + expf(-(iz + gh[768 + c])));
    float ng = tanhf(inn + rg * gh[1536 + c]);
    stc[idx] = (1.f - zg) * ng + zg * hv;
}

// logits for candidate rows: lc[t0c*512 + blk*64 + r] = s1H_row . w2 + b2
__global__ void logits_cand_k(const float* __restrict__ s1H, const float* __restrict__ w2,
                              const float* __restrict__ b2, float* __restrict__ lc, int t0c)
{
    __shared__ float red[256];
    int blk = blockIdx.x;
    int tid = threadIdx.x, r = tid >> 2, p = tid & 3;
    const float* rp = s1H + ((size_t)blk * 64 + r) * 768 + p * 192;
    const float* wp = w2 + p * 192;
    float s = 0.f;
    for (int i = 0; i < 192; i++) s = fmaf(rp[i], wp[i], s);
    red[tid] = s; __syncthreads();
    if (p == 0)
        lc[(size_t)t0c * 512 + (size_t)blk * 64 + r]
            = red[tid] + red[tid + 1] + red[tid + 2] + red[tid + 3] + b2[0];
}

// walk the argmax chain through the precomputed candidate-logits table; 64 threads
__global__ void chain_k(const float* __restrict__ lc, float* __restrict__ out)
{
    __shared__ float lrow[64];
    __shared__ int am[8];
    int tid = threadIdx.x;            // b*8 + a
    int b = tid >> 3, a = tid & 7;
    for (int t = 0; t < T_; t++) {
        int cand = (t == 0) ? 0 : am[b];
        float v = lc[t * 512 + b * 64 + cand * 8 + a];
        out[((size_t)(b * T_ + t)) * A_ + a] = v;
        lrow[tid] = v;
        __syncthreads();
        if (a == 0) {
            float best = lrow[b * 8]; int bi = 0;
            for (int x = 1; x < 8; x++) { float w = lrow[b * 8 + x]; if (w > best) { best = w; bi = x; } }
            am[b] = bi;
        }
        __syncthreads();
    }
}

// ===== host =====
static inline void MMstd(hipStream_t st, const float* A, int lda, int arpb, long abst, long aoff,
                         const float* W, long woff, int ldw, const float* bias, long boff,
                         float* C, long ldc, long coff, int M, int N, int K, int relu)
{
    dim3 g((N + 127) / 128, (M + 63) / 64, 1), b(256);
    if (relu)
        mm<1, false><<<g, b, 0, st>>>(A, lda, arpb, abst, aoff, 0, 0, 0, NP, 1,
                                      W, woff, ldw, 0, 0, 0, bias, boff, 1.f,
                                      C, 0, 0, 0, 1, ldc, 0, coff, 1, nullptr, M, N, K);
    else
        mm<0, false><<<g, b, 0, st>>>(A, lda, arpb, abst, aoff, 0, 0, 0, NP, 1,
                                      W, woff, ldw, 0, 0, 0, bias, boff, 1.f,
                                      C, 0, 0, 0, 1, ldc, 0, coff, 1, nullptr, M, N, K);
}

extern "C" void kernel_launch(void* const* d_in, const int* in_sizes, int n_in,
                              void* d_out, int out_size, void* d_ws, size_t ws_size,
                              hipStream_t stream)
{
    const float* video     = (const float*)d_in[0];
    const float* script    = (const float*)d_in[1];
    const float* question  = (const float*)d_in[2];
    const float* a_texts   = (const float*)d_in[3];
    const float* a_buttons = (const float*)d_in[4];
    const float* state0    = (const float*)d_in[5];
    const float* mlp_v_w1 = (const float*)d_in[6];  const float* mlp_v_b1 = (const float*)d_in[7];
    const float* mlp_v_w2 = (const float*)d_in[8];  const float* mlp_v_b2 = (const float*)d_in[9];
    const float* mlp_t_w1 = (const float*)d_in[10]; const float* mlp_t_b1 = (const float*)d_in[11];
    const float* mlp_t_w2 = (const float*)d_in[12]; const float* mlp_t_b2 = (const float*)d_in[13];
    const float* pre_w1   = (const float*)d_in[14]; const float* pre_b1   = (const float*)d_in[15];
    const float* pre_w2   = (const float*)d_in[16]; const float* pre_b2   = (const float*)d_in[17];
    const float* s2v_in_w = (const float*)d_in[18]; const float* s2v_in_b = (const float*)d_in[19];
    const float* s2v_out_w= (const float*)d_in[20]; const float* s2v_out_b= (const float*)d_in[21];
    const float* qa2s_in_w= (const float*)d_in[22]; const float* qa2s_in_b= (const float*)d_in[23];
    const float* qa2s_out_w=(const float*)d_in[24]; const float* qa2s_out_b=(const float*)d_in[25];
    const float* gru_w_ih = (const float*)d_in[26]; const float* gru_w_hh = (const float*)d_in[27];
    const float* gru_b_ih = (const float*)d_in[28]; const float* gru_b_hh = (const float*)d_in[29];
    const float* proj_w1  = (const float*)d_in[30]; const float* proj_b1  = (const float*)d_in[31];
    const float* proj_w2  = (const float*)d_in[32]; const float* proj_b2  = (const float*)d_in[33];
    float* out = (float*)d_out;
    (void)in_sizes; (void)n_in; (void)out_size;

    // ---- persistent region (floats) ----
    float* fb = (float*)d_ws;
    float* vid_attT = fb; fb += 786432;   // per b: [c=768][j=128]
    float* k2       = fb; fb += 786432;   // row-major 1024x768
    float* v2T      = fb; fb += 786432;   // per (b,h): [d=64][j=128]
    float* q_t      = fb; fb += 6144;
    float* gh0      = fb; fb += 2304;     // state0 @ w_hh^T + b_hh
    float* pre_all  = fb; fb += 786432;   // [t][64][768]
    float* lc       = fb; fb += 8192;     // candidate logits [t][b][ap][a]
    float* U        = fb;                 // dynamic region

    long wsF  = (long)(ws_size / 4);
    long dynF = wsF - (long)(U - (float*)d_ws) - 64;

    // phase-1 group size
    int g = 1;
    for (int c = 8; c >= 1; c >>= 1) { if (1572864L + (long)c * 1966080L <= dynF) { g = c; break; } }
    // scan chunk size (timesteps per batched pass)
    int TG = 1;
    for (int c = 16; c >= 1; c >>= 1) { if ((long)c * 1286144L <= dynF) { TG = c; break; } }
    // candidate phase: gi_all/ghall live in dyn region (used only after chunks)
    float* gi_all = U;                    // 1024x2304
    float* ghall  = U + 2359296;          // 1024x2304
    float* candU  = U + 4718592;
    long dynC = dynF - 4718592;
    int TG2 = 1;
    for (int c = 16; c >= 1; c >>= 1) { if ((long)c * 786432L <= dynC) { TG2 = c; break; } }

    // phase-1 view of U
    float* qp      = U;                   // 1024x768
    float* attnout = U + 786432;          // 1024x768
    float* bufA    = U + 1572864;                        // g*512x768 (vidH, then kp)
    float* bufB    = bufA + (size_t)g * 393216;          // g*512x768 (vid)
    float* bufD    = bufB + (size_t)g * 393216;          // vpT: per (lb,h): [d=64][j=512]
    float* sc_g    = bufD + (size_t)g * 393216;          // per z: 128x512
    float* scrH    = U + 1572864;                        // reuse group region after groups
    float* scr_t   = scrH + 786432;
    float* qH      = scrH;                               // reuse after scr_t computed

    hipStream_t st = stream;
    const long DD = (long)D_ * D_;
    dim3 blk(256);

    // ======== phase 1 ========
    MMstd(st, script, D_, NP, 0, 0, s2v_in_w, 0, D_, s2v_in_b, 0, qp, D_, 0, B_*S_, D_, D_, 0);
    for (int s0 = 0; s0 < B_; s0 += g) {
        int Mg = 512 * g;
        long voff = (long)s0 * 393216;
        MMstd(st, video, D_, NP, 0, voff, mlp_v_w1, 0, D_, mlp_v_b1, 0, bufA, D_, 0, Mg, D_, D_, 1);
        MMstd(st, bufA, D_, NP, 0, 0, mlp_v_w2, 0, D_, mlp_v_b2, 0, bufB, D_, 0, Mg, D_, D_, 0);
        MMstd(st, bufB, D_, NP, 0, 0, s2v_in_w, DD, D_, s2v_in_b, D_, bufA, D_, 0, Mg, D_, D_, 0); // kp
        {   // vpT: out o = (row/512)*393216 + row%512 + col*512
            dim3 gr(6, (unsigned)(Mg / 64), 1);
            mm<0, false><<<gr, blk, 0, st>>>(bufB, D_, NP, 0, 0, 0, 0, 0, NP, 1,
                s2v_in_w, 2*DD, D_, 0, 0, 0, s2v_in_b, 2*D_, 1.f,
                bufD, 0, 0, 0, 512, 393216, 1, 0, 512, nullptr, Mg, D_, D_);
        }
        {   // scores: sc_g[z=lb*12+h][i][j] = 0.125 * qp_row_i . kp_row_j  (dh slice h)
            dim3 gr(4, 2, (unsigned)(12 * g));
            mm<0, false><<<gr, blk, 0, st>>>(qp, D_, NP, 0, (long)s0 * 98304, 0, 98304, 64, NP, 12,
                bufA, 0, D_, 0, 393216, 64, nullptr, 0, 0.125f,
                sc_g, 0, 786432, 65536, 1, 512, 0, 0, 1, nullptr, S_, V_, 64);
        }
        softmax_rows<<<dim3((unsigned)(12 * g * 128)), blk, 0, st>>>(sc_g, 512);
        {   // PV: attnout[b*128+i][h*64+d] = P . V
            dim3 gr(1, 2, (unsigned)(12 * g));
            mm<0, false><<<gr, blk, 0, st>>>(sc_g, 512, NP, 0, 0, 0, 786432, 65536, NP, 12,
                bufD, 0, 512, 0, 393216, 32768, nullptr, 0, 1.f,
                attnout, 0, 98304, 64, 1, 768, 0, (long)s0 * 98304, 1, nullptr, S_, 64, 512);
        }
    }
    {   // vid_attT: out o = (row/128)*98304 + row%128 + col*128
        dim3 gr(6, 16, 1);
        mm<0, false><<<gr, blk, 0, st>>>(attnout, D_, NP, 0, 0, 0, 0, 0, NP, 1,
            s2v_out_w, 0, D_, 0, 0, 0, s2v_out_b, 0, 1.f,
            vid_attT, 0, 0, 0, 128, 98304, 1, 0, 128, nullptr, B_*S_, D_, D_);
    }
    MMstd(st, script, D_, NP, 0, 0, mlp_t_w1, 0, D_, mlp_t_b1, 0, scrH, D_, 0, B_*S_, D_, D_, 1);
    MMstd(st, scrH, D_, NP, 0, 0, mlp_t_w2, 0, D_, mlp_t_b2, 0, scr_t, D_, 0, B_*S_, D_, D_, 0);
    MMstd(st, scr_t, D_, NP, 0, 0, qa2s_in_w, DD, D_, qa2s_in_b, D_, k2, D_, 0, B_*S_, D_, D_, 0);
    {   // v2T: out o = (row/128)*98304 + row%128 + col*128
        dim3 gr(6, 16, 1);
        mm<0, false><<<gr, blk, 0, st>>>(scr_t, D_, NP, 0, 0, 0, 0, 0, NP, 1,
            qa2s_in_w, 2*DD, D_, 0, 0, 0, qa2s_in_b, 2*D_, 1.f,
            v2T, 0, 0, 0, 128, 98304, 1, 0, 128, nullptr, B_*S_, D_, D_);
    }
    MMstd(st, question, D_, NP, 0, 0, mlp_t_w1, 0, D_, mlp_t_b1, 0, qH, D_, 0, B_, D_, D_, 1);
    MMstd(st, qH, D_, NP, 0, 0, mlp_t_w2, 0, D_, mlp_t_b2, 0, q_t, D_, 0, B_, D_, D_, 0);

    // ======== batched scan precompute (chunks of TG timesteps) ========
    for (int t0 = 0; t0 < T_; t0 += TG) {
        // chunk view of U (row order within chunk: r = tch*64 + b*8 + a)
        float* inputs = U;                         // TG x 64 x 6144
        float* preH   = inputs + (size_t)TG * 393216;
        float* a_tH   = preH   + (size_t)TG * 393216;
        float* abH    = a_tH   + (size_t)TG * 49152;
        float* qp2    = abH    + (size_t)TG * 245760;
        float* sc2    = qp2    + (size_t)TG * 49152;   // [tch][b][h][8][128]
        float* wmaskp = sc2    + (size_t)TG * 98304;   // [tch][b][8][128]
        float* att2   = wmaskp + (size_t)TG * 8192;    // TG x 64 x 768

        // a_t layer1 (gather over t), z = tch
        mm<1, false><<<dim3(6, 1, TG), blk, 0, st>>>(a_texts, D_, A_, 98304, (long)t0 * 6144,
            0, 6144, 0, NP, 1,
            mlp_t_w1, 0, D_, 0, 0, 0, mlp_t_b1, 0, 1.f,
            a_tH, 0, 49152, 0, 1, 768, 0, 0, 1, nullptr, 64, D_, D_);
        // a_t layer2 + q_t -> inputs[:,1536:2304]
        mm<0, true><<<dim3(6, 1, TG), blk, 0, st>>>(a_tH, D_, NP, 0, 0, 0, 49152, 0, NP, 1,
            mlp_t_w2, 0, D_, 0, 0, 0, mlp_t_b2, 0, 1.f,
            inputs, 0, 393216, 0, 1, DIN_, 0, 1536, 1, q_t, 64, D_, D_);
        // a_b layer1 (gather over t)
        mm<1, false><<<dim3(6, 5, TG), blk, 0, st>>>(a_buttons, D_, A_*M_, 491520, (long)t0 * 30720,
            0, 30720, 0, NP, 1,
            mlp_v_w1, 0, D_, 0, 0, 0, mlp_v_b1, 0, 1.f,
            abH, 0, 245760, 0, 1, 768, 0, 0, 1, nullptr, 320, D_, D_);
        // a_b layer2 -> inputs[:,2304:6144]
        mm<0, false><<<dim3(6, 5, TG), blk, 0, st>>>(abH, D_, NP, 0, 0, 0, 245760, 0, NP, 1,
            mlp_v_w2, 0, D_, 0, 0, 0, mlp_v_b2, 0, 1.f,
            inputs, 0, 393216, 0, M_, DIN_, 768, 2304, 1, nullptr, 320, D_, D_);
        // qp2 = qa @ qa2s_wq
        mm<0, false><<<dim3(6, 1, TG), blk, 0, st>>>(inputs, DIN_, NP, 0, 1536, 0, 393216, 0, NP, 1,
            qa2s_in_w, 0, D_, 0, 0, 0, qa2s_in_b, 0, 1.f,
            qp2, 0, 49152, 0, 1, 768, 0, 0, 1, nullptr, 64, D_, D_);
        // scores2: z = tch*96 + b*12 + h
        mm<0, false><<<dim3(1, 1, 96 * TG), blk, 0, st>>>(qp2, D_, NP, 0, 0, 49152, 6144, 64, 8, 12,
            k2, 0, D_, 0, 98304, 64, nullptr, 0, 0.125f,
            sc2, 98304, 12288, 1024, 1, 128, 0, 0, 1, nullptr, A_, S_, 64);
        softmax_rows<<<dim3((unsigned)(768 * TG)), blk, 0, st>>>(sc2, 128);
        wmask_kernel<<<dim3((unsigned)(8 * TG)), blk, 0, st>>>(sc2, wmaskp);
        // qa_vid = wmask @ vid_att -> inputs[:,0:768]; z = tch*8 + b
        mm<0, false><<<dim3(6, 1, 8 * TG), blk, 0, st>>>(wmaskp, S_, NP, 0, 0, 0, 8192, 1024, NP, 8,
            vid_attT, 0, 128, 0, 0, 98304, nullptr, 0, 1.f,
            inputs, 0, 393216, 49152, 1, DIN_, 0, 0, 1, nullptr, A_, D_, S_);
        // PV2 -> att2; z = tch*96 + b*12 + h
        mm<0, false><<<dim3(1, 1, 96 * TG), blk, 0, st>>>(sc2, S_, NP, 0, 0, 98304, 12288, 1024, 8, 12,
            v2T, 0, 128, 0, 98304, 8192, nullptr, 0, 1.f,
            att2, 49152, 6144, 64, 1, 768, 0, 0, 1, nullptr, A_, 64, S_);
        // attn out-proj -> inputs[:,768:1536]
        mm<0, false><<<dim3(6, 1, TG), blk, 0, st>>>(att2, D_, NP, 0, 0, 0, 49152, 0, NP, 1,
            qa2s_out_w, 0, D_, 0, 0, 0, qa2s_out_b, 0, 1.f,
            inputs, 0, 393216, 0, 1, DIN_, 0, 768, 1, nullptr, 64, D_, D_);
        // pre-MLP L1 (the big batched GEMM): M = TG*64, no split-K
        mm<1, false><<<dim3(48, TG, 1), blk, 0, st>>>(inputs, DIN_, NP, 0, 0, 0, 0, 0, NP, 1,
            pre_w1, 0, DIN_, 0, 0, 0, pre_b1, 0, 1.f,
            preH, 0, 0, 0, 1, DIN_, 0, 0, 1, nullptr, TG * 64, DIN_, DIN_);
        // pre-MLP L2 -> pre_all[t0*64 ...]
        mm<0, false><<<dim3(6, TG, 1), blk, 0, st>>>(preH, DIN_, NP, 0, 0, 0, 0, 0, NP, 1,
            pre_w2, 0, DIN_, 0, 0, 0, pre_b2, 0, 1.f,
            pre_all, 0, 0, 0, 1, 768, 0, (long)t0 * 49152, 1, nullptr, TG * 64, DS_, DIN_);
    }

    // ======== GRU candidate precompute ========
    MMstd(st, pre_all, DS_, NP, 0, 0, gru_w_ih, 0, DS_, gru_b_ih, 0, gi_all, 3*DS_, 0, 1024, 3*DS_, DS_, 0);
    MMstd(st, pre_all, DS_, NP, 0, 0, gru_w_hh, 0, DS_, gru_b_hh, 0, ghall, 3*DS_, 0, 1024, 3*DS_, DS_, 0);
    MMstd(st, state0, DS_, NP, 0, 0, gru_w_hh, 0, DS_, gru_b_hh, 0, gh0, 3*DS_, 0, 1, 3*DS_, DS_, 0);

    for (int t0 = 0; t0 < T_; t0 += TG2) {
        float* stc = candU;                          // TG2*512 x 768
        float* s1H = candU + (size_t)TG2 * 393216;   // TG2*512 x 768
        gru_cand<<<dim3((unsigned)(TG2 * 1536)), blk, 0, st>>>(gi_all, ghall, gh0, pre_all,
                                                               state0, stc, t0);
        MMstd(st, stc, DS_, NP, 0, 0, proj_w1, 0, DS_, proj_b1, 0, s1H, DS_, 0, TG2 * 512, DS_, DS_, 1);
        logits_cand_k<<<dim3((unsigned)(TG2 * 8)), blk, 0, st>>>(s1H, proj_w2, proj_b2, lc, t0);
    }

    // ======== sequential argmax chain (trivial) ========
    chain_k<<<1, 64, 0, st>>>(lc, out);
}